// Round 2
// baseline (609.785 us; speedup 1.0000x reference)
//
#include <hip/hip_runtime.h>
#include <hip/hip_bf16.h>

#define DIMD 2048
#define NHD 16
#define QLORA 1536
#define KVLORA 512
#define QKD 192
#define BBD 2
#define SSD 2048
#define BSD (BBD*SSD)       // 4096 tokens
#define KVPAD 640           // 576 padded to multiple of 128
#define BHN (BBD*NHD)       // 32 (b,h) pairs
#define EPSF 1.1920929e-07f
#define SCALEF 0.07216878364870322f  // 192^-0.5 (folded into Q at build_q)

typedef __hip_bfloat16 bf16;
typedef __attribute__((ext_vector_type(8))) short short8;
typedef __attribute__((ext_vector_type(4))) float floatx4;

typedef __attribute__((address_space(1))) char as1_char;
typedef __attribute__((address_space(3))) char as3_char;
#define GLD16(g, l) __builtin_amdgcn_global_load_lds((as1_char*)(g), (as3_char*)(l), 16, 0, 0)

// ---------------- block reduction (256 threads = 4 waves) ----------------
__device__ __forceinline__ float block_sum(float x) {
#pragma unroll
  for (int o = 32; o > 0; o >>= 1) x += __shfl_xor(x, o, 64);
  __shared__ float red[4];
  __syncthreads();
  if ((threadIdx.x & 63) == 0) red[threadIdx.x >> 6] = x;
  __syncthreads();
  return red[0] + red[1] + red[2] + red[3];
}

// ---------------- generic bf16 MFMA GEMM:  C = A(MxK) * B(NxK)^T + bias ----------------
// XCD-aware bijective block swizzle (m204): each XCD gets a contiguous chunk of
// tile-space so neighboring tiles (sharing A/B panels) hit the same L2.
template<bool STORE_BF16>
__global__ __launch_bounds__(256)
void gemm_bt(const bf16* __restrict__ A, const bf16* __restrict__ Bm,
             const float* __restrict__ bias, void* __restrict__ Cp,
             int M, int N, int K, long sA, long sB, long sC, int ldc)
{
  int nwg = gridDim.x * gridDim.y;
  int lin = blockIdx.y * gridDim.x + blockIdx.x;
  int xcd = lin & 7, l8 = lin >> 3;
  int qd = nwg >> 3, rd = nwg & 7;
  int wg = (xcd < rd ? xcd * (qd + 1) : rd * (qd + 1) + (xcd - rd) * qd) + l8;
  int bx = wg % gridDim.x, by = wg / gridDim.x;

  int m0 = by * 128, n0 = bx * 128;
  long z = blockIdx.z;
  A  += z * sA;
  Bm += z * sB;

  __shared__ __align__(16) bf16 Asm[128 * 32];
  __shared__ __align__(16) bf16 Bsm[128 * 32];

  const int tid  = threadIdx.x;
  const int lane = tid & 63;
  const int wv   = tid >> 6;
  const int wm   = (wv >> 1) << 6;
  const int wn   = (wv & 1) << 6;
  const int fr   = lane & 15;
  const int q8   = (lane >> 4) << 3;

  floatx4 acc[4][4];
#pragma unroll
  for (int i = 0; i < 4; ++i)
#pragma unroll
    for (int j = 0; j < 4; ++j)
      acc[i][j] = (floatx4){0.f, 0.f, 0.f, 0.f};

  for (int k0 = 0; k0 < K; k0 += 32) {
    __syncthreads();
#pragma unroll
    for (int it = 0; it < 2; ++it) {
      int seg = it * 256 + tid;
      int row = seg >> 2, cs = seg & 3;
      GLD16(A  + (long)(m0 + row) * K + k0 + cs * 8, &Asm[(it * 256 + wv * 64) * 8]);
      GLD16(Bm + (long)(n0 + row) * K + k0 + cs * 8, &Bsm[(it * 256 + wv * 64) * 8]);
    }
    __syncthreads();

    short8 fa[4], fb[4];
#pragma unroll
    for (int t = 0; t < 4; ++t) fa[t] = *(const short8*)&Asm[(wm + t * 16 + fr) * 32 + q8];
#pragma unroll
    for (int t = 0; t < 4; ++t) fb[t] = *(const short8*)&Bsm[(wn + t * 16 + fr) * 32 + q8];
#pragma unroll
    for (int i = 0; i < 4; ++i)
#pragma unroll
      for (int j = 0; j < 4; ++j)
        acc[i][j] = __builtin_amdgcn_mfma_f32_16x16x32_bf16(fa[i], fb[j], acc[i][j], 0, 0, 0);
  }

  long cb = z * sC;
  int rq = (lane >> 4) * 4;
#pragma unroll
  for (int i = 0; i < 4; ++i) {
#pragma unroll
    for (int j = 0; j < 4; ++j) {
      int col = n0 + wn + j * 16 + fr;
      float bv = bias ? bias[col] : 0.f;
#pragma unroll
      for (int r = 0; r < 4; ++r) {
        int rowg = m0 + wm + i * 16 + rq + r;
        float v = acc[i][j][r] + bv;
        if (STORE_BF16)
          ((bf16*)Cp)[cb + (long)rowg * ldc + col] = __float2bfloat16(v);
        else
          ((float*)Cp)[cb + (long)rowg * ldc + col] = v;
      }
    }
  }
}

// ---------------- fused flash attention (causal) ----------------
// 256 threads = 4 waves, each wave owns 32 q-rows (two 16-row MFMA blocks) of a
// 128-row q-tile -> every K/V LDS fragment read feeds 2 MFMAs (half the DS
// traffic per unit work vs 16 q-rows/wave). LDS = exactly 80KB (K/V double-
// buffered, KVBLK=64; P aliases the dead K buffer after QK^T) so 2 independent
// blocks co-reside per CU (two barrier domains fill each other's stalls).
// Grid: 512 one-tile blocks; lin%32=bh keeps same-bh blocks on one XCD;
// qt = g<8 ? 15-g : g-8 balances (lin, lin+256) CU pairs at 34 iters.
__global__ __launch_bounds__(256, 2)
void flash_attn(const bf16* __restrict__ Qh, const bf16* __restrict__ Kh,
                const bf16* __restrict__ Vt, bf16* __restrict__ attnall)
{
  const int lin = blockIdx.x;
  const int bh  = lin & 31;
  const int g   = lin >> 5;             // 0..15
  const int qt  = (g < 8) ? (15 - g) : (g - 8);
  const int b = bh >> 4, h = bh & 15;

  const bf16* Qg = Qh + (long)bh * SSD * QKD;
  const bf16* Kg = Kh + (long)bh * SSD * QKD;
  const bf16* Vg = Vt + (long)bh * 128 * SSD;

  __shared__ __align__(16) bf16 KB[2][12288];  // 2 x 24KB K tiles (64 kv x 192); Q stages across both
  __shared__ __align__(16) bf16 VB[2][8192];   // 2 x 16KB V tiles (128 d x 64 kv)

  const int tid  = threadIdx.x;
  const int lane = tid & 63;
  const int wv   = tid >> 6;       // 0..3
  const int fr   = lane & 15;
  const int g4   = lane >> 4;

  // staging: row r, 16B seg s pre-swizzled -> LDS position s ^ ((r>>1)&3); linear dest
  const int kr = tid >> 2;
  const int ks = (tid & 3) ^ ((kr >> 1) & 3);
  int dv[2], sv[2];
#pragma unroll
  for (int par = 0; par < 2; ++par) {
    int rs = par * 256 + tid;
    dv[par] = rs >> 2;
    sv[par] = (rs & 3) ^ ((dv[par] >> 1) & 3);
  }
  // fragment read offsets (row*32 + swizzled 8-elem seg)
  int fsw[4];
#pragma unroll
  for (int n = 0; n < 4; ++n) {
    int row = n * 16 + fr;
    fsw[n] = row * 32 + (((g4 ^ (row >> 1)) & 3) << 3);
  }
  int vsw[8];
#pragma unroll
  for (int dn = 0; dn < 8; ++dn) {
    int row = dn * 16 + fr;
    vsw[dn] = row * 32 + (((g4 ^ (row >> 1)) & 3) << 3);
  }
  int qoff[2];
#pragma unroll
  for (int i = 0; i < 2; ++i) {
    int row = wv * 32 + i * 16 + fr;
    qoff[i] = row * 32 + (((g4 ^ (row >> 1)) & 3) << 3);
  }

  const int q0   = qt << 7;
  const int jmax = 2 * qt + 1;

  auto stageKV = [&](int jb2, bf16* kb2, bf16* vb2) {
#pragma unroll
    for (int c = 0; c < 6; ++c)
      GLD16(Kg + (long)(jb2 + kr) * QKD + c * 32 + ks * 8, kb2 + c * 2048 + tid * 8);
#pragma unroll
    for (int it = 0; it < 4; ++it) {
      int c2 = it >> 1, par = it & 1;
      GLD16(Vg + (long)dv[par] * SSD + jb2 + c2 * 32 + sv[par] * 8,
            vb2 + c2 * 4096 + (par * 256 + tid) * 8);
    }
  };

  // --- stage Q tile (48KB) across KB[0..1], pull fragments to regs ---
#pragma unroll
  for (int it = 0; it < 12; ++it) {
    int c = it >> 1, par = it & 1;
    GLD16(Qg + (long)(q0 + dv[par]) * QKD + c * 32 + sv[par] * 8,
          &KB[0][0] + c * 4096 + (par * 256 + tid) * 8);
  }
  __syncthreads();  // drain: Q visible
  short8 qf[2][6];
#pragma unroll
  for (int i = 0; i < 2; ++i)
#pragma unroll
    for (int c = 0; c < 6; ++c)
      qf[i][c] = *(const short8*)(&KB[0][0] + c * 4096 + qoff[i]);

  floatx4 oacc[2][8];
#pragma unroll
  for (int i = 0; i < 2; ++i)
#pragma unroll
    for (int n = 0; n < 8; ++n) oacc[i][n] = (floatx4){0.f, 0.f, 0.f, 0.f};
  float mi[2][4], li[2][4];
#pragma unroll
  for (int i = 0; i < 2; ++i)
#pragma unroll
    for (int r = 0; r < 4; ++r) { mi[i][r] = -1e30f; li[i][r] = 0.f; }

  __syncthreads();  // all waves read Q (full lgkm drain) before K staging overwrites

  stageKV(0, &KB[0][0], &VB[0][0]);

#pragma unroll 1
  for (int j = 0; j <= jmax; ++j) {
    const int jb = j << 6;
    if (j < jmax) {
      stageKV((j + 1) << 6, &KB[(j + 1) & 1][0], &VB[(j + 1) & 1][0]);
      asm volatile("s_waitcnt vmcnt(10)" ::: "memory");  // j's 10 loads done
    } else {
      asm volatile("s_waitcnt vmcnt(0)" ::: "memory");
    }
    __builtin_amdgcn_sched_barrier(0);
    __builtin_amdgcn_s_barrier();        // buf[j&1] ready for all waves
    __builtin_amdgcn_sched_barrier(0);

    bf16* kb = &KB[j & 1][0];
    const bf16* vb = &VB[j & 1][0];
    const bool active = (jb <= q0 + wv * 32 + 31);  // wave-uniform
    floatx4 sacc[2][4];
    if (active) {
      // ---- S = Q K^T : this wave's 32 rows x 64 cols ----
#pragma unroll
      for (int i = 0; i < 2; ++i)
#pragma unroll
        for (int n = 0; n < 4; ++n) sacc[i][n] = (floatx4){0.f, 0.f, 0.f, 0.f};
      __builtin_amdgcn_s_setprio(1);
#pragma unroll
      for (int c = 0; c < 6; ++c) {
#pragma unroll
        for (int n = 0; n < 4; ++n) {
          short8 fb = *(const short8*)(kb + c * 2048 + fsw[n]);
#pragma unroll
          for (int i = 0; i < 2; ++i)
            sacc[i][n] = __builtin_amdgcn_mfma_f32_16x16x32_bf16(qf[i][c], fb, sacc[i][n], 0, 0, 0);
        }
      }
      __builtin_amdgcn_s_setprio(0);

      // ---- online softmax (Q pre-scaled by SCALEF; 16-lane row reductions) ----
#pragma unroll
      for (int i = 0; i < 2; ++i) {
        const bool diag = (jb + 63 > q0 + wv * 32 + i * 16);
#pragma unroll
        for (int r = 0; r < 4; ++r) {
          int rowg = q0 + wv * 32 + i * 16 + g4 * 4 + r;
          if (diag) {
#pragma unroll
            for (int n = 0; n < 4; ++n)
              if ((jb + n * 16 + fr) > rowg) sacc[i][n][r] = -1e30f;
          }
          float mx = fmaxf(fmaxf(sacc[i][0][r], sacc[i][1][r]),
                           fmaxf(sacc[i][2][r], sacc[i][3][r]));
#pragma unroll
          for (int off = 1; off < 16; off <<= 1) mx = fmaxf(mx, __shfl_xor(mx, off, 64));
          float mnew = fmaxf(mi[i][r], mx);
          float alpha = __expf(mi[i][r] - mnew);
          mi[i][r] = mnew;
          float rs = 0.f;
#pragma unroll
          for (int n = 0; n < 4; ++n) {
            float pv = __expf(sacc[i][n][r] - mnew);
            sacc[i][n][r] = pv;
            rs += pv;
          }
#pragma unroll
          for (int off = 1; off < 16; off <<= 1) rs += __shfl_xor(rs, off, 64);
          li[i][r] = li[i][r] * alpha + rs;
#pragma unroll
          for (int n = 0; n < 8; ++n) oacc[i][n][r] *= alpha;
        }
      }
    }

    __builtin_amdgcn_sched_barrier(0);
    __builtin_amdgcn_s_barrier();        // all QK^T reads done -> K buffer dead, P may alias
    __builtin_amdgcn_sched_barrier(0);

    if (active) {
      // ---- P -> LDS (aliases dead KB[j&1]; per-wave private rows) ----
      bf16* pb = kb;
#pragma unroll
      for (int i = 0; i < 2; ++i) {
#pragma unroll
        for (int n = 0; n < 4; ++n) {
          int c2 = n >> 1;
          int col = (n & 1) * 16 + fr;
#pragma unroll
          for (int r = 0; r < 4; ++r) {
            int m = wv * 32 + i * 16 + g4 * 4 + r;
            int cw = (((col >> 3) ^ ((m >> 1) & 3)) << 3) | (col & 7);
            pb[c2 * 4096 + m * 32 + cw] = __float2bfloat16(sacc[i][n][r]);
          }
        }
      }
      // same-wave write->read ordering via compiler-inserted lgkmcnt

      // ---- O += P V ----
      __builtin_amdgcn_s_setprio(1);
#pragma unroll
      for (int c2 = 0; c2 < 2; ++c2) {
        short8 pf[2];
#pragma unroll
        for (int i = 0; i < 2; ++i)
          pf[i] = *(const short8*)(pb + c2 * 4096 + qoff[i]);
#pragma unroll
        for (int dn = 0; dn < 8; ++dn) {
          short8 vf = *(const short8*)(vb + c2 * 4096 + vsw[dn]);
#pragma unroll
          for (int i = 0; i < 2; ++i)
            oacc[i][dn] = __builtin_amdgcn_mfma_f32_16x16x32_bf16(pf[i], vf, oacc[i][dn], 0, 0, 0);
        }
      }
      __builtin_amdgcn_s_setprio(0);
    }

    __builtin_amdgcn_sched_barrier(0);
    __builtin_amdgcn_s_barrier();        // all P/V reads done before next staging overwrites
    __builtin_amdgcn_sched_barrier(0);
  }

  // ---- normalize and write O directly in (B,S,NH*128) layout ----
#pragma unroll
  for (int i = 0; i < 2; ++i) {
#pragma unroll
    for (int r = 0; r < 4; ++r) {
      float inv = 1.f / li[i][r];
      int m = q0 + wv * 32 + i * 16 + g4 * 4 + r;
      bf16* orow = attnall + ((long)(b * SSD + m) * NHD + h) * 128;
#pragma unroll
      for (int dn = 0; dn < 8; ++dn)
        orow[dn * 16 + fr] = __float2bfloat16(oacc[i][dn][r] * inv);
    }
  }
}

// ---------------- fused fp32 -> bf16 converts (float4-vectorized) ----------------
__device__ __forceinline__ void cvt4(const float* __restrict__ s, bf16* __restrict__ d,
                                     long se, long de) {
  float4 v = *(const float4*)(s + se);
  union { bf16 h[4]; uint2 u; } o;
  o.h[0] = __float2bfloat16(v.x); o.h[1] = __float2bfloat16(v.y);
  o.h[2] = __float2bfloat16(v.z); o.h[3] = __float2bfloat16(v.w);
  *(uint2*)(d + de) = o.u;
}

#define NX4   ((long)BSD * DIMD / 4)
#define NQD4  ((long)QLORA * DIMD / 4)
#define NQU4  ((long)3072 * QLORA / 4)
#define NKVD4 ((long)KVPAD * DIMD / 4)
#define NKVU4 ((long)4096 * KVLORA / 4)
#define NWO4  ((long)DIMD * 2048 / 4)

__global__ __launch_bounds__(256)
void cvt_all(const float* __restrict__ x, const float* __restrict__ wqd,
             const float* __restrict__ wqu, const float* __restrict__ wkvd,
             const float* __restrict__ wkvu, const float* __restrict__ wo,
             bf16* __restrict__ dx, bf16* __restrict__ dwqd, bf16* __restrict__ dwqu,
             bf16* __restrict__ dwkvd, bf16* __restrict__ dwkvu, bf16* __restrict__ dwo)
{
  long i = (long)blockIdx.x * 256 + threadIdx.x;
  if (i < NX4) { cvt4(x, dx, i * 4, i * 4); return; }
  i -= NX4;
  if (i < NQD4) { cvt4(wqd, dwqd, i * 4, i * 4); return; }
  i -= NQD4;
  if (i < NQU4) { cvt4(wqu, dwqu, i * 4, i * 4); return; }
  i -= NQU4;
  if (i < NKVD4) {
    long e = i * 4;
    long r = e >> 11;             // dst row (cols = 2048)
    if (r < 576) cvt4(wkvd, dwkvd, e, e);   // src same linear index while r < 576
    else *(uint2*)(dwkvd + e) = (uint2){0u, 0u};
    return;
  }
  i -= NKVD4;
  if (i < NKVU4) { cvt4(wkvu, dwkvu, i * 4, i * 4); return; }
  i -= NKVU4;
  if (i < NWO4) { cvt4(wo, dwo, i * 4, i * 4); return; }
}

// ---------------- rmsnorm (row per block), bf16 in (+opt fp32 bias), bf16 out ----------------
template<int L>
__global__ __launch_bounds__(256)
void rmsnorm_k(const bf16* __restrict__ in, const float* __restrict__ bias,
               const float* __restrict__ w, bf16* __restrict__ out, int ldin)
{
  constexpr int NIT = L / 256;
  long r = blockIdx.x;
  const bf16* row = in + r * ldin;
  int tid = threadIdx.x;
  float v[NIT];
  float ss = 0.f;
#pragma unroll
  for (int i = 0; i < NIT; ++i) {
    int c = tid + (i << 8);
    float x = __bfloat162float(row[c]) + (bias ? bias[c] : 0.f);
    v[i] = x;
    ss += x * x;
  }
  ss = block_sum(ss);
  float sc = rsqrtf(ss / (float)L + EPSF);
#pragma unroll
  for (int i = 0; i < NIT; ++i) {
    int c = tid + (i << 8);
    out[r * L + c] = __float2bfloat16(v[i] * sc * w[c]);
  }
}

// ---------------- build Q (rope on last 64, pre-scaled by SCALEF) -> (B,NH,S,192) bf16 ----------------
__global__ void build_q(const bf16* __restrict__ Qf, const float* __restrict__ freqs,
                        bf16* __restrict__ Qh)
{
  int idx = blockIdx.x * 256 + threadIdx.x;
  if (idx >= BSD * NHD * 96) return;
  int j = idx % 96;
  int h = (idx / 96) % NHD;
  int srow = idx / (96 * NHD);
  int s = srow & (SSD - 1);
  int b = srow >> 11;
  const bf16* src = Qf + (long)srow * (NHD * QKD) + h * QKD + 2 * j;
  float x0 = __bfloat162float(src[0]), x1 = __bfloat162float(src[1]), y0, y1;
  if (j >= 64) {
    int i = j - 64;
    float f = freqs[s * 32 + i];
    float c, sn;
    __sincosf(f, &sn, &c);
    y0 = x0 * c - x1 * sn;
    y1 = x0 * sn + x1 * c;
  } else { y0 = x0; y1 = x1; }
  bf16* dst = Qh + ((long)(b * NHD + h) * SSD + s) * QKD + 2 * j;
  dst[0] = __float2bfloat16(y0 * SCALEF);
  dst[1] = __float2bfloat16(y1 * SCALEF);
}

// ---------------- build K = [K_nope | rope(K_rope) bcast] -> (B,NH,S,192) bf16 ----------------
__global__ void build_k(const bf16* __restrict__ kvf, const bf16* __restrict__ kvkr,
                        const float* __restrict__ kvb, const float* __restrict__ freqs,
                        bf16* __restrict__ Kh)
{
  int idx = blockIdx.x * 256 + threadIdx.x;
  if (idx >= BSD * NHD * 96) return;
  int j = idx % 96;
  int h = (idx / 96) % NHD;
  int srow = idx / (96 * NHD);
  int s = srow & (SSD - 1);
  int b = srow >> 11;
  float y0, y1;
  if (j < 64) {
    const bf16* src = kvf + (long)srow * 4096 + h * 256 + 2 * j;
    y0 = __bfloat162float(src[0]); y1 = __bfloat162float(src[1]);
  } else {
    int i = j - 64;
    float x0 = __bfloat162float(kvkr[(long)srow * KVPAD + 512 + 2 * i]) + kvb[512 + 2 * i];
    float x1 = __bfloat162float(kvkr[(long)srow * KVPAD + 513 + 2 * i]) + kvb[513 + 2 * i];
    float f = freqs[s * 32 + i];
    float c, sn;
    __sincosf(f, &sn, &c);
    y0 = x0 * c - x1 * sn;
    y1 = x0 * sn + x1 * c;
  }
  bf16* dst = Kh + ((long)(b * NHD + h) * SSD + s) * QKD + 2 * j;
  dst[0] = __float2bfloat16(y0);
  dst[1] = __float2bfloat16(y1);
}

// ---------------- build V^T: kv(B,S,NH,256)[...,128:256] -> Vt (BH,128,S) bf16 ----------------
__global__ __launch_bounds__(256)
void build_vt(const bf16* __restrict__ kvf, bf16* __restrict__ Vt)
{
  __shared__ float t[32][33];
  int s0 = blockIdx.x * 32, d0 = blockIdx.y * 32, z = blockIdx.z;
  int b = z / NHD, h = z % NHD;
  int tx = threadIdx.x, ty = threadIdx.y;  // 32 x 8
#pragma unroll
  for (int r = 0; r < 4; ++r) {
    int sl = ty + r * 8;
    t[sl][tx] = __bfloat162float(kvf[(long)(b * SSD + s0 + sl) * 4096 + h * 256 + 128 + d0 + tx]);
  }
  __syncthreads();
#pragma unroll
  for (int r = 0; r < 4; ++r) {
    int dl = ty + r * 8;
    Vt[((long)z * 128 + d0 + dl) * SSD + s0 + tx] = __float2bfloat16(t[tx][dl]);
  }
}

// ---------------- diagnostic: ws too small ----------------
__global__ void diag_fill(float* out) { out[blockIdx.x * 256 + threadIdx.x] = 1000.0f; }

extern "C" void kernel_launch(void* const* d_in, const int* in_sizes, int n_in,
                              void* d_out, int out_size, void* d_ws, size_t ws_size,
                              hipStream_t stream)
{
  const float* x     = (const float*)d_in[0];
  const float* freqs = (const float*)d_in[1];
  const float* Wqd   = (const float*)d_in[3];
  const float* Wqdb  = (const float*)d_in[4];
  const float* qnw   = (const float*)d_in[5];
  const float* Wqu   = (const float*)d_in[6];
  const float* Wqub  = (const float*)d_in[7];
  const float* Wkvd  = (const float*)d_in[8];
  const float* Wkvdb = (const float*)d_in[9];
  const float* kvnw  = (const float*)d_in[10];
  const float* Wkvu  = (const float*)d_in[11];
  const float* Wkvub = (const float*)d_in[12];
  const float* Wo    = (const float*)d_in[13];
  const float* Wob   = (const float*)d_in[14];
  float* out = (float*)d_out;

  char* ws = (char*)d_ws;
  size_t off = 0;
  auto alloc = [&](size_t bytes) {
    void* p = ws + off;
    off += (bytes + 255) & ~(size_t)255;
    return p;
  };

  bf16* Wqd16  = (bf16*)alloc((size_t)QLORA * DIMD * 2);
  bf16* Wqu16  = (bf16*)alloc((size_t)3072 * QLORA * 2);
  bf16* Wkvd16 = (bf16*)alloc((size_t)KVPAD * DIMD * 2);
  bf16* Wkvu16 = (bf16*)alloc((size_t)4096 * KVLORA * 2);
  bf16* Wo16   = (bf16*)alloc((size_t)DIMD * 2048 * 2);
  bf16* x16    = (bf16*)alloc((size_t)BSD * DIMD * 2);
  bf16* Ra     = (bf16*)alloc((size_t)BSD * QLORA * 2);   // qdown, then kvkr
  bf16* Rb     = (bf16*)alloc((size_t)BSD * QLORA * 2);   // qlat, then kvlat
  bf16* Rc     = (bf16*)alloc((size_t)BSD * 4096 * 2);    // Qf, then kvf, then attnall
  bf16* Qh16   = (bf16*)alloc((size_t)BHN * SSD * QKD * 2);
  bf16* Kh16   = (bf16*)alloc((size_t)BHN * SSD * QKD * 2);
  bf16* Vt16   = (bf16*)alloc((size_t)BHN * 128 * SSD * 2);

  bf16* qdown   = Ra;  bf16* kvkr    = Ra;
  bf16* qlat16  = Rb;  bf16* kvlat16 = Rb;
  bf16* Qf      = Rc;  bf16* kvf     = Rc;  bf16* attnall = Rc;

  if (off > ws_size) { diag_fill<<<8, 256, 0, stream>>>(out); return; }

  dim3 blk(256);
  auto cdiv = [](long a, long b) { return (int)((a + b - 1) / b); };

  // --- all fp32->bf16 converts in one dispatch ---
  long tot4 = NX4 + NQD4 + NQU4 + NKVD4 + NKVU4 + NWO4;
  cvt_all<<<cdiv(tot4, 256), blk, 0, stream>>>(x, Wqd, Wqu, Wkvd, Wkvu, Wo,
                                               x16, Wqd16, Wqu16, Wkvd16, Wkvu16, Wo16);

  // --- Q path ---
  gemm_bt<true><<<dim3(QLORA / 128, BSD / 128, 1), blk, 0, stream>>>(
      x16, Wqd16, Wqdb, qdown, BSD, QLORA, DIMD, 0, 0, 0, QLORA);
  rmsnorm_k<QLORA><<<BSD, blk, 0, stream>>>(qdown, nullptr, qnw, qlat16, QLORA);
  gemm_bt<true><<<dim3(3072 / 128, BSD / 128, 1), blk, 0, stream>>>(
      qlat16, Wqu16, Wqub, Qf, BSD, 3072, QLORA, 0, 0, 0, 3072);
  build_q<<<cdiv((long)BSD * NHD * 96, 256), blk, 0, stream>>>(Qf, freqs, Qh16);

  // --- KV path ---
  gemm_bt<true><<<dim3(KVPAD / 128, BSD / 128, 1), blk, 0, stream>>>(
      x16, Wkvd16, nullptr, kvkr, BSD, KVPAD, DIMD, 0, 0, 0, KVPAD);
  rmsnorm_k<KVLORA><<<BSD, blk, 0, stream>>>(kvkr, Wkvdb, kvnw, kvlat16, KVPAD);
  gemm_bt<true><<<dim3(4096 / 128, BSD / 128, 1), blk, 0, stream>>>(
      kvlat16, Wkvu16, Wkvub, kvf, BSD, 4096, KVLORA, 0, 0, 0, 4096);
  build_k<<<cdiv((long)BSD * NHD * 96, 256), blk, 0, stream>>>(kvf, kvkr, Wkvdb, freqs, Kh16);
  build_vt<<<dim3(SSD / 32, 128 / 32, BHN), dim3(32, 8), 0, stream>>>(kvf, Vt16);

  // --- fused flash attention: 512 one-tile blocks, 2 blocks/CU ---
  flash_attn<<<dim3(512), blk, 0, stream>>>(Qh16, Kh16, Vt16, attnall);

  // --- output projection (fp32 out) ---
  gemm_bt<false><<<dim3(2048 / 128, BSD / 128, 1), blk, 0, stream>>>(
      attnall, Wo16, Wob, out, BSD, DIMD, 2048, 0, 0, 0, DIMD);
}

// Round 3
// 594.371 us; speedup vs baseline: 1.0259x; 1.0259x over previous
//
#include <hip/hip_runtime.h>
#include <hip/hip_bf16.h>

#define DIMD 2048
#define NHD 16
#define QLORA 1536
#define KVLORA 512
#define QKD 192
#define BBD 2
#define SSD 2048
#define BSD (BBD*SSD)       // 4096 tokens
#define KVPAD 640           // 576 padded to multiple of 128
#define BHN (BBD*NHD)       // 32 (b,h) pairs
#define EPSF 1.1920929e-07f
#define SCALEF 0.07216878364870322f  // 192^-0.5 (folded into Q at build_q)

typedef __hip_bfloat16 bf16;
typedef __attribute__((ext_vector_type(8))) short short8;
typedef __attribute__((ext_vector_type(4))) float floatx4;

typedef __attribute__((address_space(1))) char as1_char;
typedef __attribute__((address_space(3))) char as3_char;
#define GLD16(g, l) __builtin_amdgcn_global_load_lds((as1_char*)(g), (as3_char*)(l), 16, 0, 0)

// ---------------- block reduction (256 threads = 4 waves) ----------------
__device__ __forceinline__ float block_sum(float x) {
#pragma unroll
  for (int o = 32; o > 0; o >>= 1) x += __shfl_xor(x, o, 64);
  __shared__ float red[4];
  __syncthreads();
  if ((threadIdx.x & 63) == 0) red[threadIdx.x >> 6] = x;
  __syncthreads();
  return red[0] + red[1] + red[2] + red[3];
}

// ---------------- generic bf16 MFMA GEMM:  C = A(MxK) * B(NxK)^T + bias ----------------
// XCD-aware bijective block swizzle (m204).
template<bool STORE_BF16>
__global__ __launch_bounds__(256)
void gemm_bt(const bf16* __restrict__ A, const bf16* __restrict__ Bm,
             const float* __restrict__ bias, void* __restrict__ Cp,
             int M, int N, int K, long sA, long sB, long sC, int ldc)
{
  int nwg = gridDim.x * gridDim.y;
  int lin = blockIdx.y * gridDim.x + blockIdx.x;
  int xcd = lin & 7, l8 = lin >> 3;
  int qd = nwg >> 3, rd = nwg & 7;
  int wg = (xcd < rd ? xcd * (qd + 1) : rd * (qd + 1) + (xcd - rd) * qd) + l8;
  int bx = wg % gridDim.x, by = wg / gridDim.x;

  int m0 = by * 128, n0 = bx * 128;
  long z = blockIdx.z;
  A  += z * sA;
  Bm += z * sB;

  __shared__ __align__(16) bf16 Asm[128 * 32];
  __shared__ __align__(16) bf16 Bsm[128 * 32];

  const int tid  = threadIdx.x;
  const int lane = tid & 63;
  const int wv   = tid >> 6;
  const int wm   = (wv >> 1) << 6;
  const int wn   = (wv & 1) << 6;
  const int fr   = lane & 15;
  const int q8   = (lane >> 4) << 3;

  floatx4 acc[4][4];
#pragma unroll
  for (int i = 0; i < 4; ++i)
#pragma unroll
    for (int j = 0; j < 4; ++j)
      acc[i][j] = (floatx4){0.f, 0.f, 0.f, 0.f};

  for (int k0 = 0; k0 < K; k0 += 32) {
    __syncthreads();
#pragma unroll
    for (int it = 0; it < 2; ++it) {
      int seg = it * 256 + tid;
      int row = seg >> 2, cs = seg & 3;
      GLD16(A  + (long)(m0 + row) * K + k0 + cs * 8, &Asm[(it * 256 + wv * 64) * 8]);
      GLD16(Bm + (long)(n0 + row) * K + k0 + cs * 8, &Bsm[(it * 256 + wv * 64) * 8]);
    }
    __syncthreads();

    short8 fa[4], fb[4];
#pragma unroll
    for (int t = 0; t < 4; ++t) fa[t] = *(const short8*)&Asm[(wm + t * 16 + fr) * 32 + q8];
#pragma unroll
    for (int t = 0; t < 4; ++t) fb[t] = *(const short8*)&Bsm[(wn + t * 16 + fr) * 32 + q8];
#pragma unroll
    for (int i = 0; i < 4; ++i)
#pragma unroll
      for (int j = 0; j < 4; ++j)
        acc[i][j] = __builtin_amdgcn_mfma_f32_16x16x32_bf16(fa[i], fb[j], acc[i][j], 0, 0, 0);
  }

  long cb = z * sC;
  int rq = (lane >> 4) * 4;
#pragma unroll
  for (int i = 0; i < 4; ++i) {
#pragma unroll
    for (int j = 0; j < 4; ++j) {
      int col = n0 + wn + j * 16 + fr;
      float bv = bias ? bias[col] : 0.f;
#pragma unroll
      for (int r = 0; r < 4; ++r) {
        int rowg = m0 + wm + i * 16 + rq + r;
        float v = acc[i][j][r] + bv;
        if (STORE_BF16)
          ((bf16*)Cp)[cb + (long)rowg * ldc + col] = __float2bfloat16(v);
        else
          ((float*)Cp)[cb + (long)rowg * ldc + col] = v;
      }
    }
  }
}

// ---------------- fused flash attention (causal) ----------------
// 256 threads = 4 waves, each wave owns 32 q-rows (two 16-row blocks) of a
// 128-row q-tile: every K/V LDS fragment feeds 2 MFMAs. KVBLK=32, K/V
// double-buffered + wave-private P, all in ONE 48KB LDS array (Q stages
// through it at tile start) -> 2 blocks/CU co-resident (96KB < 160KB pool;
// R2 lesson: 2x80KB does NOT fit).
// Softmax: lane-partial li (no sum-shfl in loop; one reduce at end) and
// max-reduce/rescale only when __any(partial_max > mi) -- exact math.
// Grid: 512 one-tile blocks; lin&31=bh keeps same-bh on one XCD; qt mapping
// makes blocks i and i+256 complementary (round-robin pairing balances CUs).
__global__ __launch_bounds__(256, 2)
void flash_attn(const bf16* __restrict__ Qh, const bf16* __restrict__ Kh,
                const bf16* __restrict__ Vt, bf16* __restrict__ attnall)
{
  const int lin = blockIdx.x;
  const int bh  = lin & 31;
  const int g   = lin >> 5;             // 0..15
  const int qt  = (g < 8) ? (15 - g) : (g - 8);
  const int b = bh >> 4, h = bh & 15;

  const bf16* Qg = Qh + (long)bh * SSD * QKD;
  const bf16* Kg = Kh + (long)bh * SSD * QKD;
  const bf16* Vg = Vt + (long)bh * 128 * SSD;

  // 48KB: K 2x[6 chunks x 32r x 32c] | V 2x[128d x 32s] | P [128r x 32c]
  __shared__ __align__(16) bf16 SM[24576];
  bf16* KBb0 = SM;            // 6144 elem
  bf16* KBb1 = SM + 6144;
  bf16* VBb0 = SM + 12288;    // 4096 elem
  bf16* VBb1 = SM + 16384;
  bf16* PB   = SM + 20480;    // 4096 elem

  const int tid  = threadIdx.x;
  const int lane = tid & 63;
  const int wv   = tid >> 6;       // 0..3
  const int fr   = lane & 15;
  const int g4   = lane >> 4;

  // ---- staging tables (16B seg s pre-swizzled: s ^= (row>>1)&3; linear LDS dest) ----
  long kofs[3]; int kdst[3];
#pragma unroll
  for (int it = 0; it < 3; ++it) {
    int seg = it * 256 + tid;          // 0..767 over 6 chunks x 32 rows x 4 segs
    int c = seg >> 7, rs = seg & 127;
    int r = rs >> 2, s = (rs & 3) ^ ((r >> 1) & 3);
    kofs[it] = (long)r * QKD + c * 32 + s * 8;
    kdst[it] = c * 1024 + rs * 8;
  }
  long vofs[2]; int vdst[2];
#pragma unroll
  for (int it = 0; it < 2; ++it) {
    int seg = it * 256 + tid;          // 0..511 over 128 d-rows x 4 segs
    int d = seg >> 2, s = (seg & 3) ^ ((d >> 1) & 3);
    vofs[it] = (long)d * SSD + s * 8;
    vdst[it] = seg * 8;
  }
  // ---- fragment read offsets (row*32 + swizzled 8-elem seg) ----
  int fsw[2];
#pragma unroll
  for (int n = 0; n < 2; ++n) {
    int row = n * 16 + fr;
    fsw[n] = row * 32 + (((g4 ^ (row >> 1)) & 3) << 3);
  }
  int vsw[8];
#pragma unroll
  for (int dn = 0; dn < 8; ++dn) {
    int row = dn * 16 + fr;
    vsw[dn] = row * 32 + (((g4 ^ (row >> 1)) & 3) << 3);
  }
  int qoff[2];
#pragma unroll
  for (int i = 0; i < 2; ++i) {
    int row = wv * 32 + i * 16 + fr;
    qoff[i] = row * 32 + (((g4 ^ (row >> 1)) & 3) << 3);
  }

  const int q0   = qt << 7;
  const int jmax = 4 * qt + 3;   // KVBLK=32

  // --- stage Q tile (48KB) through the whole SM, pull fragments ---
#pragma unroll
  for (int it = 0; it < 12; ++it) {
    int seg = it * 256 + tid;          // 0..3071 over 6 chunks x 128 rows x 4 segs
    int c = seg >> 9, rs = seg & 511;
    int r = rs >> 2, s = (rs & 3) ^ ((r >> 1) & 3);
    GLD16(Qg + (long)(q0 + r) * QKD + c * 32 + s * 8, SM + c * 4096 + rs * 8);
  }
  __syncthreads();  // Q visible
  short8 qf[2][6];
#pragma unroll
  for (int i = 0; i < 2; ++i)
#pragma unroll
    for (int c = 0; c < 6; ++c)
      qf[i][c] = *(const short8*)(SM + c * 4096 + qoff[i]);

  floatx4 oacc[2][8];
#pragma unroll
  for (int i = 0; i < 2; ++i)
#pragma unroll
    for (int n = 0; n < 8; ++n) oacc[i][n] = (floatx4){0.f, 0.f, 0.f, 0.f};
  float mi[2][4], li[2][4];
#pragma unroll
  for (int i = 0; i < 2; ++i)
#pragma unroll
    for (int r = 0; r < 4; ++r) { mi[i][r] = -1e30f; li[i][r] = 0.f; }

  __syncthreads();  // all qf reads done before K/V staging overwrites

  auto stageKV = [&](int jb2, bf16* kb2, bf16* vb2) {
#pragma unroll
    for (int it = 0; it < 3; ++it)
      GLD16(Kg + (long)jb2 * QKD + kofs[it], kb2 + kdst[it]);
#pragma unroll
    for (int it = 0; it < 2; ++it)
      GLD16(Vg + jb2 + vofs[it], vb2 + vdst[it]);
  };

  stageKV(0, KBb0, VBb0);

#pragma unroll 1
  for (int j = 0; j <= jmax; ++j) {
    const int jb = j << 5;
    if (j < jmax) {
      stageKV((j + 1) << 5, (j & 1) ? KBb0 : KBb1, (j & 1) ? VBb0 : VBb1);
      asm volatile("s_waitcnt vmcnt(5)" ::: "memory");  // j's 5 loads done
    } else {
      asm volatile("s_waitcnt vmcnt(0)" ::: "memory");
    }
    __builtin_amdgcn_sched_barrier(0);
    __builtin_amdgcn_s_barrier();        // buf[j&1] ready for all waves
    __builtin_amdgcn_sched_barrier(0);

    const bf16* kb = (j & 1) ? KBb1 : KBb0;
    const bf16* vb = (j & 1) ? VBb1 : VBb0;
    const bool active = (jb <= q0 + wv * 32 + 31);  // wave-uniform
    if (active) {
      // ---- S = Q K^T : this wave's 32 rows x 32 cols ----
      floatx4 sacc[2][2];
#pragma unroll
      for (int i = 0; i < 2; ++i)
#pragma unroll
        for (int n = 0; n < 2; ++n) sacc[i][n] = (floatx4){0.f, 0.f, 0.f, 0.f};
      __builtin_amdgcn_s_setprio(1);
#pragma unroll
      for (int c = 0; c < 6; ++c) {
#pragma unroll
        for (int n = 0; n < 2; ++n) {
          short8 fb = *(const short8*)(kb + c * 1024 + fsw[n]);
#pragma unroll
          for (int i = 0; i < 2; ++i)
            sacc[i][n] = __builtin_amdgcn_mfma_f32_16x16x32_bf16(qf[i][c], fb, sacc[i][n], 0, 0, 0);
        }
      }
      __builtin_amdgcn_s_setprio(0);

      // ---- online softmax, shuffle-light ----
      float pm[2][4];
#pragma unroll
      for (int i = 0; i < 2; ++i) {
        const int rbase = q0 + wv * 32 + i * 16;
        const bool diag = (jb + 31 > rbase);
#pragma unroll
        for (int r = 0; r < 4; ++r) {
          if (diag) {
            int rowg = rbase + g4 * 4 + r;
#pragma unroll
            for (int n = 0; n < 2; ++n)
              if ((jb + n * 16 + fr) > rowg) sacc[i][n][r] = -1e30f;
          }
          pm[i][r] = fmaxf(sacc[i][0][r], sacc[i][1][r]);
        }
      }
      int nn = 0;
#pragma unroll
      for (int i = 0; i < 2; ++i)
#pragma unroll
        for (int r = 0; r < 4; ++r) nn |= (pm[i][r] > mi[i][r]);
      if (__any(nn)) {
#pragma unroll
        for (int i = 0; i < 2; ++i) {
#pragma unroll
          for (int r = 0; r < 4; ++r) {
            float mx = pm[i][r];
#pragma unroll
            for (int off = 1; off < 16; off <<= 1) mx = fmaxf(mx, __shfl_xor(mx, off, 64));
            float mnew = fmaxf(mi[i][r], mx);
            float alpha = __expf(mi[i][r] - mnew);
            mi[i][r] = mnew;
            li[i][r] *= alpha;
#pragma unroll
            for (int n = 0; n < 8; ++n) oacc[i][n][r] *= alpha;
          }
        }
      }
      // exp + lane-partial row-sum (no cross-lane in loop)
#pragma unroll
      for (int i = 0; i < 2; ++i) {
#pragma unroll
        for (int r = 0; r < 4; ++r) {
          float s0 = __expf(sacc[i][0][r] - mi[i][r]);
          float s1 = __expf(sacc[i][1][r] - mi[i][r]);
          sacc[i][0][r] = s0; sacc[i][1][r] = s1;
          li[i][r] += s0 + s1;
        }
      }

      // ---- P -> LDS (wave-private rows; same-wave lgkm ordering) ----
#pragma unroll
      for (int i = 0; i < 2; ++i) {
#pragma unroll
        for (int n = 0; n < 2; ++n) {
          int col = n * 16 + fr;
#pragma unroll
          for (int r = 0; r < 4; ++r) {
            int m = wv * 32 + i * 16 + g4 * 4 + r;
            int cw = (((col >> 3) ^ ((m >> 1) & 3)) << 3) | (col & 7);
            PB[m * 32 + cw] = __float2bfloat16(sacc[i][n][r]);
          }
        }
      }

      // ---- O += P V (single k-step: KVBLK=32) ----
      short8 pf0 = *(const short8*)(PB + qoff[0]);
      short8 pf1 = *(const short8*)(PB + qoff[1]);
      __builtin_amdgcn_s_setprio(1);
#pragma unroll
      for (int dn = 0; dn < 8; ++dn) {
        short8 vf = *(const short8*)(vb + vsw[dn]);
        oacc[0][dn] = __builtin_amdgcn_mfma_f32_16x16x32_bf16(pf0, vf, oacc[0][dn], 0, 0, 0);
        oacc[1][dn] = __builtin_amdgcn_mfma_f32_16x16x32_bf16(pf1, vf, oacc[1][dn], 0, 0, 0);
      }
      __builtin_amdgcn_s_setprio(0);
    }

    __builtin_amdgcn_sched_barrier(0);
    __builtin_amdgcn_s_barrier();        // all reads of buf[j&1] done before overwrite
    __builtin_amdgcn_sched_barrier(0);
  }

  // ---- final li reduce (once), normalize, write O in (B,S,NH*128) ----
#pragma unroll
  for (int i = 0; i < 2; ++i) {
#pragma unroll
    for (int r = 0; r < 4; ++r) {
      float l = li[i][r];
#pragma unroll
      for (int off = 1; off < 16; off <<= 1) l += __shfl_xor(l, off, 64);
      float inv = 1.f / l;
      int m = q0 + wv * 32 + i * 16 + g4 * 4 + r;
      bf16* orow = attnall + ((long)(b * SSD + m) * NHD + h) * 128;
#pragma unroll
      for (int dn = 0; dn < 8; ++dn)
        orow[dn * 16 + fr] = __float2bfloat16(oacc[i][dn][r] * inv);
    }
  }
}

// ---------------- fused fp32 -> bf16 converts (float4-vectorized) ----------------
__device__ __forceinline__ void cvt4(const float* __restrict__ s, bf16* __restrict__ d,
                                     long se, long de) {
  float4 v = *(const float4*)(s + se);
  union { bf16 h[4]; uint2 u; } o;
  o.h[0] = __float2bfloat16(v.x); o.h[1] = __float2bfloat16(v.y);
  o.h[2] = __float2bfloat16(v.z); o.h[3] = __float2bfloat16(v.w);
  *(uint2*)(d + de) = o.u;
}

#define NX4   ((long)BSD * DIMD / 4)
#define NQD4  ((long)QLORA * DIMD / 4)
#define NQU4  ((long)3072 * QLORA / 4)
#define NKVD4 ((long)KVPAD * DIMD / 4)
#define NKVU4 ((long)4096 * KVLORA / 4)
#define NWO4  ((long)DIMD * 2048 / 4)

__global__ __launch_bounds__(256)
void cvt_all(const float* __restrict__ x, const float* __restrict__ wqd,
             const float* __restrict__ wqu, const float* __restrict__ wkvd,
             const float* __restrict__ wkvu, const float* __restrict__ wo,
             bf16* __restrict__ dx, bf16* __restrict__ dwqd, bf16* __restrict__ dwqu,
             bf16* __restrict__ dwkvd, bf16* __restrict__ dwkvu, bf16* __restrict__ dwo)
{
  long i = (long)blockIdx.x * 256 + threadIdx.x;
  if (i < NX4) { cvt4(x, dx, i * 4, i * 4); return; }
  i -= NX4;
  if (i < NQD4) { cvt4(wqd, dwqd, i * 4, i * 4); return; }
  i -= NQD4;
  if (i < NQU4) { cvt4(wqu, dwqu, i * 4, i * 4); return; }
  i -= NQU4;
  if (i < NKVD4) {
    long e = i * 4;
    long r = e >> 11;             // dst row (cols = 2048)
    if (r < 576) cvt4(wkvd, dwkvd, e, e);   // src same linear index while r < 576
    else *(uint2*)(dwkvd + e) = (uint2){0u, 0u};
    return;
  }
  i -= NKVD4;
  if (i < NKVU4) { cvt4(wkvu, dwkvu, i * 4, i * 4); return; }
  i -= NKVU4;
  if (i < NWO4) { cvt4(wo, dwo, i * 4, i * 4); return; }
}

// ---------------- rmsnorm (row per block), bf16 in (+opt fp32 bias), bf16 out ----------------
template<int L>
__global__ __launch_bounds__(256)
void rmsnorm_k(const bf16* __restrict__ in, const float* __restrict__ bias,
               const float* __restrict__ w, bf16* __restrict__ out, int ldin)
{
  constexpr int NIT = L / 256;
  long r = blockIdx.x;
  const bf16* row = in + r * ldin;
  int tid = threadIdx.x;
  float v[NIT];
  float ss = 0.f;
#pragma unroll
  for (int i = 0; i < NIT; ++i) {
    int c = tid + (i << 8);
    float x = __bfloat162float(row[c]) + (bias ? bias[c] : 0.f);
    v[i] = x;
    ss += x * x;
  }
  ss = block_sum(ss);
  float sc = rsqrtf(ss / (float)L + EPSF);
#pragma unroll
  for (int i = 0; i < NIT; ++i) {
    int c = tid + (i << 8);
    out[r * L + c] = __float2bfloat16(v[i] * sc * w[c]);
  }
}

// ---------------- build Q (rope on last 64, pre-scaled by SCALEF) -> (B,NH,S,192) bf16 ----------------
__global__ void build_q(const bf16* __restrict__ Qf, const float* __restrict__ freqs,
                        bf16* __restrict__ Qh)
{
  int idx = blockIdx.x * 256 + threadIdx.x;
  if (idx >= BSD * NHD * 96) return;
  int j = idx % 96;
  int h = (idx / 96) % NHD;
  int srow = idx / (96 * NHD);
  int s = srow & (SSD - 1);
  int b = srow >> 11;
  const bf16* src = Qf + (long)srow * (NHD * QKD) + h * QKD + 2 * j;
  float x0 = __bfloat162float(src[0]), x1 = __bfloat162float(src[1]), y0, y1;
  if (j >= 64) {
    int i = j - 64;
    float f = freqs[s * 32 + i];
    float c, sn;
    __sincosf(f, &sn, &c);
    y0 = x0 * c - x1 * sn;
    y1 = x0 * sn + x1 * c;
  } else { y0 = x0; y1 = x1; }
  bf16* dst = Qh + ((long)(b * NHD + h) * SSD + s) * QKD + 2 * j;
  dst[0] = __float2bfloat16(y0 * SCALEF);
  dst[1] = __float2bfloat16(y1 * SCALEF);
}

// ---------------- build K = [K_nope | rope(K_rope) bcast] -> (B,NH,S,192) bf16 ----------------
__global__ void build_k(const bf16* __restrict__ kvf, const bf16* __restrict__ kvkr,
                        const float* __restrict__ kvb, const float* __restrict__ freqs,
                        bf16* __restrict__ Kh)
{
  int idx = blockIdx.x * 256 + threadIdx.x;
  if (idx >= BSD * NHD * 96) return;
  int j = idx % 96;
  int h = (idx / 96) % NHD;
  int srow = idx / (96 * NHD);
  int s = srow & (SSD - 1);
  int b = srow >> 11;
  float y0, y1;
  if (j < 64) {
    const bf16* src = kvf + (long)srow * 4096 + h * 256 + 2 * j;
    y0 = __bfloat162float(src[0]); y1 = __bfloat162float(src[1]);
  } else {
    int i = j - 64;
    float x0 = __bfloat162float(kvkr[(long)srow * KVPAD + 512 + 2 * i]) + kvb[512 + 2 * i];
    float x1 = __bfloat162float(kvkr[(long)srow * KVPAD + 513 + 2 * i]) + kvb[513 + 2 * i];
    float f = freqs[s * 32 + i];
    float c, sn;
    __sincosf(f, &sn, &c);
    y0 = x0 * c - x1 * sn;
    y1 = x0 * sn + x1 * c;
  }
  bf16* dst = Kh + ((long)(b * NHD + h) * SSD + s) * QKD + 2 * j;
  dst[0] = __float2bfloat16(y0);
  dst[1] = __float2bfloat16(y1);
}

// ---------------- build V^T: kv(B,S,NH,256)[...,128:256] -> Vt (BH,128,S) bf16 ----------------
__global__ __launch_bounds__(256)
void build_vt(const bf16* __restrict__ kvf, bf16* __restrict__ Vt)
{
  __shared__ float t[32][33];
  int s0 = blockIdx.x * 32, d0 = blockIdx.y * 32, z = blockIdx.z;
  int b = z / NHD, h = z % NHD;
  int tx = threadIdx.x, ty = threadIdx.y;  // 32 x 8
#pragma unroll
  for (int r = 0; r < 4; ++r) {
    int sl = ty + r * 8;
    t[sl][tx] = __bfloat162float(kvf[(long)(b * SSD + s0 + sl) * 4096 + h * 256 + 128 + d0 + tx]);
  }
  __syncthreads();
#pragma unroll
  for (int r = 0; r < 4; ++r) {
    int dl = ty + r * 8;
    Vt[((long)z * 128 + d0 + dl) * SSD + s0 + tx] = __float2bfloat16(t[tx][dl]);
  }
}

// ---------------- diagnostic: ws too small ----------------
__global__ void diag_fill(float* out) { out[blockIdx.x * 256 + threadIdx.x] = 1000.0f; }

extern "C" void kernel_launch(void* const* d_in, const int* in_sizes, int n_in,
                              void* d_out, int out_size, void* d_ws, size_t ws_size,
                              hipStream_t stream)
{
  const float* x     = (const float*)d_in[0];
  const float* freqs = (const float*)d_in[1];
  const float* Wqd   = (const float*)d_in[3];
  const float* Wqdb  = (const float*)d_in[4];
  const float* qnw   = (const float*)d_in[5];
  const float* Wqu   = (const float*)d_in[6];
  const float* Wqub  = (const float*)d_in[7];
  const float* Wkvd  = (const float*)d_in[8];
  const float* Wkvdb = (const float*)d_in[9];
  const float* kvnw  = (const float*)d_in[10];
  const float* Wkvu  = (const float*)d_in[11];
  const float* Wkvub = (const float*)d_in[12];
  const float* Wo    = (const float*)d_in[13];
  const float* Wob   = (const float*)d_in[14];
  float* out = (float*)d_out;

  char* ws = (char*)d_ws;
  size_t off = 0;
  auto alloc = [&](size_t bytes) {
    void* p = ws + off;
    off += (bytes + 255) & ~(size_t)255;
    return p;
  };

  bf16* Wqd16  = (bf16*)alloc((size_t)QLORA * DIMD * 2);
  bf16* Wqu16  = (bf16*)alloc((size_t)3072 * QLORA * 2);
  bf16* Wkvd16 = (bf16*)alloc((size_t)KVPAD * DIMD * 2);
  bf16* Wkvu16 = (bf16*)alloc((size_t)4096 * KVLORA * 2);
  bf16* Wo16   = (bf16*)alloc((size_t)DIMD * 2048 * 2);
  bf16* x16    = (bf16*)alloc((size_t)BSD * DIMD * 2);
  bf16* Ra     = (bf16*)alloc((size_t)BSD * QLORA * 2);   // qdown, then kvkr
  bf16* Rb     = (bf16*)alloc((size_t)BSD * QLORA * 2);   // qlat, then kvlat
  bf16* Rc     = (bf16*)alloc((size_t)BSD * 4096 * 2);    // Qf, then kvf, then attnall
  bf16* Qh16   = (bf16*)alloc((size_t)BHN * SSD * QKD * 2);
  bf16* Kh16   = (bf16*)alloc((size_t)BHN * SSD * QKD * 2);
  bf16* Vt16   = (bf16*)alloc((size_t)BHN * 128 * SSD * 2);

  bf16* qdown   = Ra;  bf16* kvkr    = Ra;
  bf16* qlat16  = Rb;  bf16* kvlat16 = Rb;
  bf16* Qf      = Rc;  bf16* kvf     = Rc;  bf16* attnall = Rc;

  if (off > ws_size) { diag_fill<<<8, 256, 0, stream>>>(out); return; }

  dim3 blk(256);
  auto cdiv = [](long a, long b) { return (int)((a + b - 1) / b); };

  // --- all fp32->bf16 converts in one dispatch ---
  long tot4 = NX4 + NQD4 + NQU4 + NKVD4 + NKVU4 + NWO4;
  cvt_all<<<cdiv(tot4, 256), blk, 0, stream>>>(x, Wqd, Wqu, Wkvd, Wkvu, Wo,
                                               x16, Wqd16, Wqu16, Wkvd16, Wkvu16, Wo16);

  // --- Q path ---
  gemm_bt<true><<<dim3(QLORA / 128, BSD / 128, 1), blk, 0, stream>>>(
      x16, Wqd16, Wqdb, qdown, BSD, QLORA, DIMD, 0, 0, 0, QLORA);
  rmsnorm_k<QLORA><<<BSD, blk, 0, stream>>>(qdown, nullptr, qnw, qlat16, QLORA);
  gemm_bt<true><<<dim3(3072 / 128, BSD / 128, 1), blk, 0, stream>>>(
      qlat16, Wqu16, Wqub, Qf, BSD, 3072, QLORA, 0, 0, 0, 3072);
  build_q<<<cdiv((long)BSD * NHD * 96, 256), blk, 0, stream>>>(Qf, freqs, Qh16);

  // --- KV path ---
  gemm_bt<true><<<dim3(KVPAD / 128, BSD / 128, 1), blk, 0, stream>>>(
      x16, Wkvd16, nullptr, kvkr, BSD, KVPAD, DIMD, 0, 0, 0, KVPAD);
  rmsnorm_k<KVLORA><<<BSD, blk, 0, stream>>>(kvkr, Wkvdb, kvnw, kvlat16, KVPAD);
  gemm_bt<true><<<dim3(4096 / 128, BSD / 128, 1), blk, 0, stream>>>(
      kvlat16, Wkvu16, Wkvub, kvf, BSD, 4096, KVLORA, 0, 0, 0, 4096);
  build_k<<<cdiv((long)BSD * NHD * 96, 256), blk, 0, stream>>>(kvf, kvkr, Wkvdb, freqs, Kh16);
  build_vt<<<dim3(SSD / 32, 128 / 32, BHN), dim3(32, 8), 0, stream>>>(kvf, Vt16);

  // --- fused flash attention: 512 one-tile blocks, 2 blocks/CU ---
  flash_attn<<<dim3(512), blk, 0, stream>>>(Qh16, Kh16, Vt16, attnall);

  // --- output projection (fp32 out) ---
  gemm_bt<false><<<dim3(2048 / 128, BSD / 128, 1), blk, 0, stream>>>(
      attnall, Wo16, Wob, out, BSD, DIMD, 2048, 0, 0, 0, DIMD);
}

// Round 4
// 561.938 us; speedup vs baseline: 1.0851x; 1.0577x over previous
//
#include <hip/hip_runtime.h>
#include <hip/hip_bf16.h>

#define DIMD 2048
#define NHD 16
#define QLORA 1536
#define KVLORA 512
#define QKD 192
#define BBD 2
#define SSD 2048
#define BSD (BBD*SSD)       // 4096 tokens
#define KVPAD 640           // 576 padded to multiple of 128
#define BHN (BBD*NHD)       // 32 (b,h) pairs
#define EPSF 1.1920929e-07f
#define SCALEF 0.07216878364870322f  // 192^-0.5 (folded into Q at build_q)

typedef __hip_bfloat16 bf16;
typedef __attribute__((ext_vector_type(8))) short short8;
typedef __attribute__((ext_vector_type(4))) float floatx4;

typedef __attribute__((address_space(1))) char as1_char;
typedef __attribute__((address_space(3))) char as3_char;
#define GLD16(g, l) __builtin_amdgcn_global_load_lds((as1_char*)(g), (as3_char*)(l), 16, 0, 0)

// ---------------- block reduction (256 threads = 4 waves) ----------------
__device__ __forceinline__ float block_sum(float x) {
#pragma unroll
  for (int o = 32; o > 0; o >>= 1) x += __shfl_xor(x, o, 64);
  __shared__ float red[4];
  __syncthreads();
  if ((threadIdx.x & 63) == 0) red[threadIdx.x >> 6] = x;
  __syncthreads();
  return red[0] + red[1] + red[2] + red[3];
}

// ---------------- generic bf16 MFMA GEMM:  C = A(MxK) * B(NxK)^T + bias ----------------
// XCD-aware bijective block swizzle (m204).
template<bool STORE_BF16>
__global__ __launch_bounds__(256)
void gemm_bt(const bf16* __restrict__ A, const bf16* __restrict__ Bm,
             const float* __restrict__ bias, void* __restrict__ Cp,
             int M, int N, int K, long sA, long sB, long sC, int ldc)
{
  int nwg = gridDim.x * gridDim.y;
  int lin = blockIdx.y * gridDim.x + blockIdx.x;
  int xcd = lin & 7, l8 = lin >> 3;
  int qd = nwg >> 3, rd = nwg & 7;
  int wg = (xcd < rd ? xcd * (qd + 1) : rd * (qd + 1) + (xcd - rd) * qd) + l8;
  int bx = wg % gridDim.x, by = wg / gridDim.x;

  int m0 = by * 128, n0 = bx * 128;
  long z = blockIdx.z;
  A  += z * sA;
  Bm += z * sB;

  __shared__ __align__(16) bf16 Asm[128 * 32];
  __shared__ __align__(16) bf16 Bsm[128 * 32];

  const int tid  = threadIdx.x;
  const int lane = tid & 63;
  const int wv   = tid >> 6;
  const int wm   = (wv >> 1) << 6;
  const int wn   = (wv & 1) << 6;
  const int fr   = lane & 15;
  const int q8   = (lane >> 4) << 3;

  floatx4 acc[4][4];
#pragma unroll
  for (int i = 0; i < 4; ++i)
#pragma unroll
    for (int j = 0; j < 4; ++j)
      acc[i][j] = (floatx4){0.f, 0.f, 0.f, 0.f};

  for (int k0 = 0; k0 < K; k0 += 32) {
    __syncthreads();
#pragma unroll
    for (int it = 0; it < 2; ++it) {
      int seg = it * 256 + tid;
      int row = seg >> 2, cs = seg & 3;
      GLD16(A  + (long)(m0 + row) * K + k0 + cs * 8, &Asm[(it * 256 + wv * 64) * 8]);
      GLD16(Bm + (long)(n0 + row) * K + k0 + cs * 8, &Bsm[(it * 256 + wv * 64) * 8]);
    }
    __syncthreads();

    short8 fa[4], fb[4];
#pragma unroll
    for (int t = 0; t < 4; ++t) fa[t] = *(const short8*)&Asm[(wm + t * 16 + fr) * 32 + q8];
#pragma unroll
    for (int t = 0; t < 4; ++t) fb[t] = *(const short8*)&Bsm[(wn + t * 16 + fr) * 32 + q8];
#pragma unroll
    for (int i = 0; i < 4; ++i)
#pragma unroll
      for (int j = 0; j < 4; ++j)
        acc[i][j] = __builtin_amdgcn_mfma_f32_16x16x32_bf16(fa[i], fb[j], acc[i][j], 0, 0, 0);
  }

  long cb = z * sC;
  int rq = (lane >> 4) * 4;
#pragma unroll
  for (int i = 0; i < 4; ++i) {
#pragma unroll
    for (int j = 0; j < 4; ++j) {
      int col = n0 + wn + j * 16 + fr;
      float bv = bias ? bias[col] : 0.f;
#pragma unroll
      for (int r = 0; r < 4; ++r) {
        int rowg = m0 + wm + i * 16 + rq + r;
        float v = acc[i][j][r] + bv;
        if (STORE_BF16)
          ((bf16*)Cp)[cb + (long)rowg * ldc + col] = __float2bfloat16(v);
        else
          ((float*)Cp)[cb + (long)rowg * ldc + col] = v;
      }
    }
  }
}

// ---------------- fused flash attention (causal), two tiles per block ----------------
// 512 threads = 8 waves (2 waves/SIMD TLP for the whole block lifetime).
// Waves 0-3 own q-tile A (qtA=15-p), waves 4-7 own q-tile B (qtB=p); K/V are
// staged ONCE for both tiles over the union j-range (A's). Each wave owns 32
// q-rows (two 16-row MFMA blocks): every K/V LDS fragment feeds 2 MFMAs.
// KVBLK=64 double-buffered, counted vmcnt(5), 2 raw s_barriers/iter.
// LDS 112KB: K 2x24KB | V 2x16KB | P 32KB (dedicated; 256 rows x 64).
// Q (96KB, both tiles) stages through the K/V area before the loop.
// Softmax: lane-partial li (reduced once at end), max-rescale only when
// __any(partial_max > mi) -- exact math. Grid: 256 blocks (1/CU);
// lin&31=bh keeps same-bh blocks on one XCD; per-block iters 32-2p.
__global__ __launch_bounds__(512, 2)
void flash_attn(const bf16* __restrict__ Qh, const bf16* __restrict__ Kh,
                const bf16* __restrict__ Vt, bf16* __restrict__ attnall)
{
  const int lin = blockIdx.x;
  const int bh  = lin & 31;
  const int p   = lin >> 5;            // 0..7
  const int qtA = 15 - p;
  const int b = bh >> 4, h = bh & 15;

  const bf16* Qg = Qh + (long)bh * SSD * QKD;
  const bf16* Kg = Kh + (long)bh * SSD * QKD;
  const bf16* Vg = Vt + (long)bh * 128 * SSD;

  // 112KB
  __shared__ __align__(16) bf16 SM[57344];
  bf16* KB0 = SM;            // 12288 elem (6 chunks x 64 r x 32)
  bf16* KB1 = SM + 12288;
  bf16* VB0 = SM + 24576;    // 8192 elem (2 chunks x 128 d x 32)
  bf16* VB1 = SM + 32768;
  bf16* PB  = SM + 40960;    // 16384 elem (2 chunks x 256 m x 32)

  const int tid  = threadIdx.x;
  const int lane = tid & 63;
  const int wv   = tid >> 6;       // 0..7
  const int w4   = wv & 3;
  const int tb   = wv >> 2;        // 0 = tile A, 1 = tile B
  const int fr   = lane & 15;
  const int g4   = lane >> 4;

  const int qt    = tb ? (p) : (qtA);
  const int qbase = qt << 7;
  const int jmax  = 2 * qtA + 1;   // union staging range (A is the larger tile)

  // ---- staging tables (16B seg s pre-swizzled: s ^= (row>>1)&3; linear LDS dest) ----
  long kofs[3]; int kdst[3];
#pragma unroll
  for (int it = 0; it < 3; ++it) {
    int seg = it * 512 + tid;          // 0..1535 = 6 chunks x 64 rows x 4 segs
    int c = seg >> 8, rs = seg & 255;
    int r = rs >> 2, s = (rs & 3) ^ ((r >> 1) & 3);
    kofs[it] = (long)r * QKD + c * 32 + s * 8;
    kdst[it] = c * 2048 + rs * 8;
  }
  long vofs[2]; int vdst[2];
#pragma unroll
  for (int it = 0; it < 2; ++it) {
    int seg = it * 512 + tid;          // 0..1023 = 2 chunks x 128 d x 4 segs
    int c2 = seg >> 9, ds = seg & 511;
    int d = ds >> 2, s = (ds & 3) ^ ((d >> 1) & 3);
    vofs[it] = (long)d * SSD + c2 * 32 + s * 8;
    vdst[it] = c2 * 4096 + ds * 8;
  }
  // ---- fragment read offsets (row*32 + swizzled 8-elem seg) ----
  int fsw[4];
#pragma unroll
  for (int n = 0; n < 4; ++n) {
    int row = n * 16 + fr;
    fsw[n] = row * 32 + (((g4 ^ (row >> 1)) & 3) << 3);
  }
  int vsw[8];
#pragma unroll
  for (int dn = 0; dn < 8; ++dn) {
    int row = dn * 16 + fr;
    vsw[dn] = row * 32 + (((g4 ^ (row >> 1)) & 3) << 3);
  }
  int qoff[2];                         // staged-Q/P row = wv*32 + i*16 + fr
#pragma unroll
  for (int i = 0; i < 2; ++i) {
    int row = wv * 32 + i * 16 + fr;
    qoff[i] = row * 32 + (((g4 ^ (row >> 1)) & 3) << 3);
  }

  // --- stage both Q tiles (96KB: rows 0..127 = A, 128..255 = B) ---
  const int qbA = qtA << 7, qbB = p << 7;
#pragma unroll
  for (int it = 0; it < 12; ++it) {
    int seg = it * 512 + tid;          // 0..6143 = 6 chunks x 256 rows x 4 segs
    int c = seg >> 10, rs = seg & 1023;
    int r = rs >> 2, s = (rs & 3) ^ ((r >> 1) & 3);
    int grow = (r < 128) ? (qbA + r) : (qbB + r - 128);
    GLD16(Qg + (long)grow * QKD + c * 32 + s * 8, SM + c * 8192 + rs * 8);
  }
  __syncthreads();  // Q visible
  short8 qf[2][6];
#pragma unroll
  for (int i = 0; i < 2; ++i)
#pragma unroll
    for (int c = 0; c < 6; ++c)
      qf[i][c] = *(const short8*)(SM + c * 8192 + qoff[i]);

  floatx4 oacc[2][8];
#pragma unroll
  for (int i = 0; i < 2; ++i)
#pragma unroll
    for (int n = 0; n < 8; ++n) oacc[i][n] = (floatx4){0.f, 0.f, 0.f, 0.f};
  float mi[2][4], li[2][4];
#pragma unroll
  for (int i = 0; i < 2; ++i)
#pragma unroll
    for (int r = 0; r < 4; ++r) { mi[i][r] = -1e30f; li[i][r] = 0.f; }

  __syncthreads();  // all qf reads done before K/V staging overwrites

  auto stageKV = [&](int jb2, bf16* kb2, bf16* vb2) {
#pragma unroll
    for (int it = 0; it < 3; ++it)
      GLD16(Kg + (long)jb2 * QKD + kofs[it], kb2 + kdst[it]);
#pragma unroll
    for (int it = 0; it < 2; ++it)
      GLD16(Vg + jb2 + vofs[it], vb2 + vdst[it]);
  };

  stageKV(0, KB0, VB0);

#pragma unroll 1
  for (int j = 0; j <= jmax; ++j) {
    const int jb = j << 6;
    if (j < jmax) {
      stageKV((j + 1) << 6, (j & 1) ? KB0 : KB1, (j & 1) ? VB0 : VB1);
      asm volatile("s_waitcnt vmcnt(5)" ::: "memory");  // j's 5 loads done
    } else {
      asm volatile("s_waitcnt vmcnt(0)" ::: "memory");
    }
    __builtin_amdgcn_sched_barrier(0);
    __builtin_amdgcn_s_barrier();        // buf[j&1] ready for all waves
    __builtin_amdgcn_sched_barrier(0);

    const bf16* kb = (j & 1) ? KB1 : KB0;
    const bf16* vb = (j & 1) ? VB1 : VB0;
    const bool active = (jb <= qbase + w4 * 32 + 31);  // wave-uniform
    if (active) {
      // ---- S = Q K^T : this wave's 32 rows x 64 cols ----
      floatx4 sacc[2][4];
#pragma unroll
      for (int i = 0; i < 2; ++i)
#pragma unroll
        for (int n = 0; n < 4; ++n) sacc[i][n] = (floatx4){0.f, 0.f, 0.f, 0.f};
      __builtin_amdgcn_s_setprio(1);
#pragma unroll
      for (int c = 0; c < 6; ++c) {
#pragma unroll
        for (int n = 0; n < 4; ++n) {
          short8 fb = *(const short8*)(kb + c * 2048 + fsw[n]);
#pragma unroll
          for (int i = 0; i < 2; ++i)
            sacc[i][n] = __builtin_amdgcn_mfma_f32_16x16x32_bf16(qf[i][c], fb, sacc[i][n], 0, 0, 0);
        }
      }
      __builtin_amdgcn_s_setprio(0);

      // ---- online softmax, shuffle-light ----
      float pm[2][4];
#pragma unroll
      for (int i = 0; i < 2; ++i) {
        const int rbase = qbase + w4 * 32 + i * 16;
        const bool diag = (jb + 63 > rbase);
#pragma unroll
        for (int r = 0; r < 4; ++r) {
          if (diag) {
            int rowg = rbase + g4 * 4 + r;
#pragma unroll
            for (int n = 0; n < 4; ++n)
              if ((jb + n * 16 + fr) > rowg) sacc[i][n][r] = -1e30f;
          }
          pm[i][r] = fmaxf(fmaxf(sacc[i][0][r], sacc[i][1][r]),
                           fmaxf(sacc[i][2][r], sacc[i][3][r]));
        }
      }
      int nn = 0;
#pragma unroll
      for (int i = 0; i < 2; ++i)
#pragma unroll
        for (int r = 0; r < 4; ++r) nn |= (pm[i][r] > mi[i][r]);
      if (__any(nn)) {
#pragma unroll
        for (int i = 0; i < 2; ++i) {
#pragma unroll
          for (int r = 0; r < 4; ++r) {
            float mx = pm[i][r];
#pragma unroll
            for (int off = 1; off < 16; off <<= 1) mx = fmaxf(mx, __shfl_xor(mx, off, 64));
            float mnew = fmaxf(mi[i][r], mx);
            float alpha = __expf(mi[i][r] - mnew);
            mi[i][r] = mnew;
            li[i][r] *= alpha;
#pragma unroll
            for (int n = 0; n < 8; ++n) oacc[i][n][r] *= alpha;
          }
        }
      }
      // exp + lane-partial row-sum (no cross-lane in loop)
#pragma unroll
      for (int i = 0; i < 2; ++i) {
#pragma unroll
        for (int r = 0; r < 4; ++r) {
          float acc = 0.f;
#pragma unroll
          for (int n = 0; n < 4; ++n) {
            float pv = __expf(sacc[i][n][r] - mi[i][r]);
            sacc[i][n][r] = pv;
            acc += pv;
          }
          li[i][r] += acc;
        }
      }

      // ---- P -> LDS (wave-private rows; same-wave lgkm ordering) ----
#pragma unroll
      for (int i = 0; i < 2; ++i) {
#pragma unroll
        for (int n = 0; n < 4; ++n) {
          int c2 = n >> 1;
          int col = (n & 1) * 16 + fr;
#pragma unroll
          for (int r = 0; r < 4; ++r) {
            int m = wv * 32 + i * 16 + g4 * 4 + r;
            int cw = (((col >> 3) ^ ((m >> 1) & 3)) << 3) | (col & 7);
            PB[c2 * 8192 + m * 32 + cw] = __float2bfloat16(sacc[i][n][r]);
          }
        }
      }

      // ---- O += P V (2 k-steps) ----
      __builtin_amdgcn_s_setprio(1);
#pragma unroll
      for (int c2 = 0; c2 < 2; ++c2) {
        short8 pf[2];
#pragma unroll
        for (int i = 0; i < 2; ++i)
          pf[i] = *(const short8*)(PB + c2 * 8192 + qoff[i]);
#pragma unroll
        for (int dn = 0; dn < 8; ++dn) {
          short8 vf = *(const short8*)(vb + c2 * 4096 + vsw[dn]);
#pragma unroll
          for (int i = 0; i < 2; ++i)
            oacc[i][dn] = __builtin_amdgcn_mfma_f32_16x16x32_bf16(pf[i], vf, oacc[i][dn], 0, 0, 0);
        }
      }
      __builtin_amdgcn_s_setprio(0);
    }

    __builtin_amdgcn_sched_barrier(0);
    __builtin_amdgcn_s_barrier();        // all reads of buf[j&1] done before overwrite
    __builtin_amdgcn_sched_barrier(0);
  }

  // ---- final li reduce (once), normalize, write O in (B,S,NH*128) ----
#pragma unroll
  for (int i = 0; i < 2; ++i) {
#pragma unroll
    for (int r = 0; r < 4; ++r) {
      float l = li[i][r];
#pragma unroll
      for (int off = 1; off < 16; off <<= 1) l += __shfl_xor(l, off, 64);
      float inv = 1.f / l;
      int m = qbase + w4 * 32 + i * 16 + g4 * 4 + r;
      bf16* orow = attnall + ((long)(b * SSD + m) * NHD + h) * 128;
#pragma unroll
      for (int dn = 0; dn < 8; ++dn)
        orow[dn * 16 + fr] = __float2bfloat16(oacc[i][dn][r] * inv);
    }
  }
}

// ---------------- fused fp32 -> bf16 converts (float4-vectorized) ----------------
__device__ __forceinline__ void cvt4(const float* __restrict__ s, bf16* __restrict__ d,
                                     long se, long de) {
  float4 v = *(const float4*)(s + se);
  union { bf16 h[4]; uint2 u; } o;
  o.h[0] = __float2bfloat16(v.x); o.h[1] = __float2bfloat16(v.y);
  o.h[2] = __float2bfloat16(v.z); o.h[3] = __float2bfloat16(v.w);
  *(uint2*)(d + de) = o.u;
}

#define NX4   ((long)BSD * DIMD / 4)
#define NQD4  ((long)QLORA * DIMD / 4)
#define NQU4  ((long)3072 * QLORA / 4)
#define NKVD4 ((long)KVPAD * DIMD / 4)
#define NKVU4 ((long)4096 * KVLORA / 4)
#define NWO4  ((long)DIMD * 2048 / 4)

__global__ __launch_bounds__(256)
void cvt_all(const float* __restrict__ x, const float* __restrict__ wqd,
             const float* __restrict__ wqu, const float* __restrict__ wkvd,
             const float* __restrict__ wkvu, const float* __restrict__ wo,
             bf16* __restrict__ dx, bf16* __restrict__ dwqd, bf16* __restrict__ dwqu,
             bf16* __restrict__ dwkvd, bf16* __restrict__ dwkvu, bf16* __restrict__ dwo)
{
  long i = (long)blockIdx.x * 256 + threadIdx.x;
  if (i < NX4) { cvt4(x, dx, i * 4, i * 4); return; }
  i -= NX4;
  if (i < NQD4) { cvt4(wqd, dwqd, i * 4, i * 4); return; }
  i -= NQD4;
  if (i < NQU4) { cvt4(wqu, dwqu, i * 4, i * 4); return; }
  i -= NQU4;
  if (i < NKVD4) {
    long e = i * 4;
    long r = e >> 11;             // dst row (cols = 2048)
    if (r < 576) cvt4(wkvd, dwkvd, e, e);   // src same linear index while r < 576
    else *(uint2*)(dwkvd + e) = (uint2){0u, 0u};
    return;
  }
  i -= NKVD4;
  if (i < NKVU4) { cvt4(wkvu, dwkvu, i * 4, i * 4); return; }
  i -= NKVU4;
  if (i < NWO4) { cvt4(wo, dwo, i * 4, i * 4); return; }
}

// ---------------- rmsnorm (row per block), bf16 in (+opt fp32 bias), bf16 out ----------------
template<int L>
__global__ __launch_bounds__(256)
void rmsnorm_k(const bf16* __restrict__ in, const float* __restrict__ bias,
               const float* __restrict__ w, bf16* __restrict__ out, int ldin)
{
  constexpr int NIT = L / 256;
  long r = blockIdx.x;
  const bf16* row = in + r * ldin;
  int tid = threadIdx.x;
  float v[NIT];
  float ss = 0.f;
#pragma unroll
  for (int i = 0; i < NIT; ++i) {
    int c = tid + (i << 8);
    float x = __bfloat162float(row[c]) + (bias ? bias[c] : 0.f);
    v[i] = x;
    ss += x * x;
  }
  ss = block_sum(ss);
  float sc = rsqrtf(ss / (float)L + EPSF);
#pragma unroll
  for (int i = 0; i < NIT; ++i) {
    int c = tid + (i << 8);
    out[r * L + c] = __float2bfloat16(v[i] * sc * w[c]);
  }
}

// ---------------- build Q (rope on last 64, pre-scaled by SCALEF) -> (B,NH,S,192) bf16 ----------------
__global__ void build_q(const bf16* __restrict__ Qf, const float* __restrict__ freqs,
                        bf16* __restrict__ Qh)
{
  int idx = blockIdx.x * 256 + threadIdx.x;
  if (idx >= BSD * NHD * 96) return;
  int j = idx % 96;
  int h = (idx / 96) % NHD;
  int srow = idx / (96 * NHD);
  int s = srow & (SSD - 1);
  int b = srow >> 11;
  const bf16* src = Qf + (long)srow * (NHD * QKD) + h * QKD + 2 * j;
  float x0 = __bfloat162float(src[0]), x1 = __bfloat162float(src[1]), y0, y1;
  if (j >= 64) {
    int i = j - 64;
    float f = freqs[s * 32 + i];
    float c, sn;
    __sincosf(f, &sn, &c);
    y0 = x0 * c - x1 * sn;
    y1 = x0 * sn + x1 * c;
  } else { y0 = x0; y1 = x1; }
  bf16* dst = Qh + ((long)(b * NHD + h) * SSD + s) * QKD + 2 * j;
  dst[0] = __float2bfloat16(y0 * SCALEF);
  dst[1] = __float2bfloat16(y1 * SCALEF);
}

// ---------------- build K = [K_nope | rope(K_rope) bcast] -> (B,NH,S,192) bf16 ----------------
__global__ void build_k(const bf16* __restrict__ kvf, const bf16* __restrict__ kvkr,
                        const float* __restrict__ kvb, const float* __restrict__ freqs,
                        bf16* __restrict__ Kh)
{
  int idx = blockIdx.x * 256 + threadIdx.x;
  if (idx >= BSD * NHD * 96) return;
  int j = idx % 96;
  int h = (idx / 96) % NHD;
  int srow = idx / (96 * NHD);
  int s = srow & (SSD - 1);
  int b = srow >> 11;
  float y0, y1;
  if (j < 64) {
    const bf16* src = kvf + (long)srow * 4096 + h * 256 + 2 * j;
    y0 = __bfloat162float(src[0]); y1 = __bfloat162float(src[1]);
  } else {
    int i = j - 64;
    float x0 = __bfloat162float(kvkr[(long)srow * KVPAD + 512 + 2 * i]) + kvb[512 + 2 * i];
    float x1 = __bfloat162float(kvkr[(long)srow * KVPAD + 513 + 2 * i]) + kvb[513 + 2 * i];
    float f = freqs[s * 32 + i];
    float c, sn;
    __sincosf(f, &sn, &c);
    y0 = x0 * c - x1 * sn;
    y1 = x0 * sn + x1 * c;
  }
  bf16* dst = Kh + ((long)(b * NHD + h) * SSD + s) * QKD + 2 * j;
  dst[0] = __float2bfloat16(y0);
  dst[1] = __float2bfloat16(y1);
}

// ---------------- build V^T: kv(B,S,NH,256)[...,128:256] -> Vt (BH,128,S) bf16 ----------------
__global__ __launch_bounds__(256)
void build_vt(const bf16* __restrict__ kvf, bf16* __restrict__ Vt)
{
  __shared__ float t[32][33];
  int s0 = blockIdx.x * 32, d0 = blockIdx.y * 32, z = blockIdx.z;
  int b = z / NHD, h = z % NHD;
  int tx = threadIdx.x, ty = threadIdx.y;  // 32 x 8
#pragma unroll
  for (int r = 0; r < 4; ++r) {
    int sl = ty + r * 8;
    t[sl][tx] = __bfloat162float(kvf[(long)(b * SSD + s0 + sl) * 4096 + h * 256 + 128 + d0 + tx]);
  }
  __syncthreads();
#pragma unroll
  for (int r = 0; r < 4; ++r) {
    int dl = ty + r * 8;
    Vt[((long)z * 128 + d0 + dl) * SSD + s0 + tx] = __float2bfloat16(t[tx][dl]);
  }
}

// ---------------- diagnostic: ws too small ----------------
__global__ void diag_fill(float* out) { out[blockIdx.x * 256 + threadIdx.x] = 1000.0f; }

extern "C" void kernel_launch(void* const* d_in, const int* in_sizes, int n_in,
                              void* d_out, int out_size, void* d_ws, size_t ws_size,
                              hipStream_t stream)
{
  const float* x     = (const float*)d_in[0];
  const float* freqs = (const float*)d_in[1];
  const float* Wqd   = (const float*)d_in[3];
  const float* Wqdb  = (const float*)d_in[4];
  const float* qnw   = (const float*)d_in[5];
  const float* Wqu   = (const float*)d_in[6];
  const float* Wqub  = (const float*)d_in[7];
  const float* Wkvd  = (const float*)d_in[8];
  const float* Wkvdb = (const float*)d_in[9];
  const float* kvnw  = (const float*)d_in[10];
  const float* Wkvu  = (const float*)d_in[11];
  const float* Wkvub = (const float*)d_in[12];
  const float* Wo    = (const float*)d_in[13];
  const float* Wob   = (const float*)d_in[14];
  float* out = (float*)d_out;

  char* ws = (char*)d_ws;
  size_t off = 0;
  auto alloc = [&](size_t bytes) {
    void* p = ws + off;
    off += (bytes + 255) & ~(size_t)255;
    return p;
  };

  bf16* Wqd16  = (bf16*)alloc((size_t)QLORA * DIMD * 2);
  bf16* Wqu16  = (bf16*)alloc((size_t)3072 * QLORA * 2);
  bf16* Wkvd16 = (bf16*)alloc((size_t)KVPAD * DIMD * 2);
  bf16* Wkvu16 = (bf16*)alloc((size_t)4096 * KVLORA * 2);
  bf16* Wo16   = (bf16*)alloc((size_t)DIMD * 2048 * 2);
  bf16* x16    = (bf16*)alloc((size_t)BSD * DIMD * 2);
  bf16* Ra     = (bf16*)alloc((size_t)BSD * QLORA * 2);   // qdown, then kvkr
  bf16* Rb     = (bf16*)alloc((size_t)BSD * QLORA * 2);   // qlat, then kvlat
  bf16* Rc     = (bf16*)alloc((size_t)BSD * 4096 * 2);    // Qf, then kvf, then attnall
  bf16* Qh16   = (bf16*)alloc((size_t)BHN * SSD * QKD * 2);
  bf16* Kh16   = (bf16*)alloc((size_t)BHN * SSD * QKD * 2);
  bf16* Vt16   = (bf16*)alloc((size_t)BHN * 128 * SSD * 2);

  bf16* qdown   = Ra;  bf16* kvkr    = Ra;
  bf16* qlat16  = Rb;  bf16* kvlat16 = Rb;
  bf16* Qf      = Rc;  bf16* kvf     = Rc;  bf16* attnall = Rc;

  if (off > ws_size) { diag_fill<<<8, 256, 0, stream>>>(out); return; }

  dim3 blk(256);
  auto cdiv = [](long a, long b) { return (int)((a + b - 1) / b); };

  // --- all fp32->bf16 converts in one dispatch ---
  long tot4 = NX4 + NQD4 + NQU4 + NKVD4 + NKVU4 + NWO4;
  cvt_all<<<cdiv(tot4, 256), blk, 0, stream>>>(x, Wqd, Wqu, Wkvd, Wkvu, Wo,
                                               x16, Wqd16, Wqu16, Wkvd16, Wkvu16, Wo16);

  // --- Q path ---
  gemm_bt<true><<<dim3(QLORA / 128, BSD / 128, 1), blk, 0, stream>>>(
      x16, Wqd16, Wqdb, qdown, BSD, QLORA, DIMD, 0, 0, 0, QLORA);
  rmsnorm_k<QLORA><<<BSD, blk, 0, stream>>>(qdown, nullptr, qnw, qlat16, QLORA);
  gemm_bt<true><<<dim3(3072 / 128, BSD / 128, 1), blk, 0, stream>>>(
      qlat16, Wqu16, Wqub, Qf, BSD, 3072, QLORA, 0, 0, 0, 3072);
  build_q<<<cdiv((long)BSD * NHD * 96, 256), blk, 0, stream>>>(Qf, freqs, Qh16);

  // --- KV path ---
  gemm_bt<true><<<dim3(KVPAD / 128, BSD / 128, 1), blk, 0, stream>>>(
      x16, Wkvd16, nullptr, kvkr, BSD, KVPAD, DIMD, 0, 0, 0, KVPAD);
  rmsnorm_k<KVLORA><<<BSD, blk, 0, stream>>>(kvkr, Wkvdb, kvnw, kvlat16, KVPAD);
  gemm_bt<true><<<dim3(4096 / 128, BSD / 128, 1), blk, 0, stream>>>(
      kvlat16, Wkvu16, Wkvub, kvf, BSD, 4096, KVLORA, 0, 0, 0, 4096);
  build_k<<<cdiv((long)BSD * NHD * 96, 256), blk, 0, stream>>>(kvf, kvkr, Wkvdb, freqs, Kh16);
  build_vt<<<dim3(SSD / 32, 128 / 32, BHN), dim3(32, 8), 0, stream>>>(kvf, Vt16);

  // --- fused flash attention: 256 two-tile blocks (1/CU), 8 waves each ---
  flash_attn<<<dim3(256), dim3(512), 0, stream>>>(Qh16, Kh16, Vt16, attnall);

  // --- output projection (fp32 out) ---
  gemm_bt<false><<<dim3(2048 / 128, BSD / 128, 1), blk, 0, stream>>>(
      attnall, Wo16, Wob, out, BSD, DIMD, 2048, 0, 0, 0, DIMD);
}